// Round 2
// baseline (571.986 us; speedup 1.0000x reference)
//
#include <hip/hip_runtime.h>

// VQ nearest-neighbor: N=65536 queries (32*2048), DIM=64, K=1024 codes, fp32.
// argmin_k( csq[k] - 2*dot(z_n, c_k) )  [z_sq dropped: constant per query,
// cannot change the argmin]. out[n] = codebook[argmin].
//
// Structure: block = 4 waves x 64 queries. Wave w scans a 256-code chunk with
// wave-uniform k (codebook reads become scalar s_loads, SGPR broadcast).
// K-split x4 lifts total waves 1024 -> 4096 (16 waves/CU, ~50% occupancy --
// the max once the 64-float z row occupies 64+ VGPRs). LDS reduction combines
// chunk winners in chunk order to preserve jnp.argmin first-min tie-break.

constexpr int KCODES = 1024;
constexpr int DIM = 64;
constexpr int WPB = 4;               // waves per block (K-split factor)
constexpr int CHUNK = KCODES / WPB;  // 256 codes per wave
constexpr int QPB = 64;              // queries per block (one per lane)
constexpr int BLOCK = WPB * 64;

__global__ __launch_bounds__(BLOCK, 4) void vq_kernel(
    const float* __restrict__ z, const float* __restrict__ cb,
    float* __restrict__ out) {
    __shared__ float scsq[KCODES];
    __shared__ float sbestd[BLOCK];
    __shared__ int sbestk[BLOCK];
    __shared__ int sidx[QPB];

    const int lane = threadIdx.x & 63;
    const int wave = threadIdx.x >> 6;
    const int kbase = wave * CHUNK;

    // Phase A: codebook norms for this wave's chunk (lane-parallel, fused
    // so no separate csq kernel/launch).
#pragma unroll
    for (int j = 0; j < CHUNK / 64; ++j) {
        const int k = kbase + j * 64 + lane;
        const float4* c4 = (const float4*)(cb + k * DIM);
        float s0 = 0.f, s1 = 0.f, s2 = 0.f, s3 = 0.f;
#pragma unroll
        for (int e = 0; e < DIM / 4; ++e) {
            const float4 v = c4[e];
            s0 = fmaf(v.x, v.x, s0);
            s1 = fmaf(v.y, v.y, s1);
            s2 = fmaf(v.z, v.z, s2);
            s3 = fmaf(v.w, v.w, s3);
        }
        scsq[k] = (s0 + s1) + (s2 + s3);
    }

    // Phase B: this lane's query row -> 16 float4 registers (64 VGPRs).
    const int q = blockIdx.x * QPB + lane;
    float4 zr[DIM / 4];
    const float4* zp = (const float4*)(z + (size_t)q * DIM);
#pragma unroll
    for (int e = 0; e < DIM / 4; ++e) zr[e] = zp[e];

    __syncthreads();

    // Phase C: scan this wave's chunk. Codebook address is wave-uniform ->
    // scalar loads; 64 fp32 FMAs per k with 4-way accumulator ILP.
    float best = 3.402823466e38f;
    int bestk = kbase;
#pragma unroll 2
    for (int k = kbase; k < kbase + CHUNK; ++k) {
        const float* c = cb + k * DIM;
        float d0 = 0.f, d1 = 0.f, d2 = 0.f, d3 = 0.f;
#pragma unroll
        for (int e = 0; e < DIM / 4; ++e) {
            d0 = fmaf(zr[e].x, c[4 * e + 0], d0);
            d1 = fmaf(zr[e].y, c[4 * e + 1], d1);
            d2 = fmaf(zr[e].z, c[4 * e + 2], d2);
            d3 = fmaf(zr[e].w, c[4 * e + 3], d3);
        }
        const float dot = (d0 + d1) + (d2 + d3);
        const float dist = fmaf(-2.0f, dot, scsq[k]);
        if (dist < best) { best = dist; bestk = k; }  // strict <: first-min wins
    }

    sbestd[threadIdx.x] = best;
    sbestk[threadIdx.x] = bestk;
    __syncthreads();

    // Phase D: combine the WPB chunk winners in chunk order (ties -> lower k).
    if (wave == 0) {
        float b = sbestd[lane];
        int bk = sbestk[lane];
#pragma unroll
        for (int w = 1; w < WPB; ++w) {
            const float d = sbestd[w * 64 + lane];
            const int kk = sbestk[w * 64 + lane];
            if (d < b) { b = d; bk = kk; }
        }
        sidx[lane] = bk;
    }
    __syncthreads();

    // Epilogue: gather winning rows, coalesced float4 writes (cb is L2-hot).
    float4* out4 = (float4*)(out + (size_t)blockIdx.x * QPB * DIM);
    constexpr int F = QPB * DIM / 4;  // 1024 float4s per block
#pragma unroll
    for (int f = threadIdx.x; f < F; f += BLOCK) {
        const int qq = f >> 4;   // query within block
        const int e4 = f & 15;   // float4 within row
        out4[f] = ((const float4*)(cb + (size_t)sidx[qq] * DIM))[e4];
    }
}

extern "C" void kernel_launch(void* const* d_in, const int* in_sizes, int n_in,
                              void* d_out, int out_size, void* d_ws, size_t ws_size,
                              hipStream_t stream) {
    const float* z = (const float*)d_in[0];
    const float* cb = (const float*)d_in[1];
    float* out = (float*)d_out;

    const int nq = in_sizes[0] / DIM;  // 65536
    vq_kernel<<<nq / QPB, BLOCK, 0, stream>>>(z, cb, out);
}

// Round 3
// 184.983 us; speedup vs baseline: 3.0921x; 3.0921x over previous
//
#include <hip/hip_runtime.h>

// VQ nearest-neighbor: N=65536 queries (32*2048), DIM=64, K=1024 codes, fp32.
// argmin_k( csq[k] - 2*dot(z_n, c_k) ); out[n] = codebook[argmin].
//
// Register-blocked GEMM structure: block = 256 threads = 16(tx: codes) x
// 16(ty: queries). Each thread owns an 8x8 micro-tile: queries q=ty+16i,
// codes c=tx+16j. Per d4-step (float4 chunk of the 64-dim contraction) a
// thread loads 8+8 float4 fragments from LDS and issues 256 fp32 FMAs ->
// the FMA:load ratio (8x better than one-query-per-thread) plus 64
// independent acc chains supply the ILP that rounds 1/2 lacked.
// Pure-VALU floor: 4.3e9 MACs /64 lanes *2cyc /1024 SIMDs ~= 55 us.

constexpr int KCODES = 1024;
constexpr int DIM = 64;
constexpr int D4 = DIM / 4;           // 16 float4 chunks per row
constexpr int MQ = 128;               // queries per block
constexpr int NK = 128;               // codes per LDS tile
constexpr int NTILES = KCODES / NK;   // 8
constexpr int BLOCK = 256;
constexpr int PAD = NK + 1;           // float4 row stride (pad breaks conflicts)

// Shared layout (bytes). zt4 region is aliased by the argmin-reduction
// arrays in the epilogue (all zt4 reads complete by then).
constexpr int SM_ZT = 0;                       // 16*129 float4 = 33024
constexpr int SM_CT = 33024;                   // 16*129 float4 = 33024
constexpr int SM_CSQ = 66048;                  // 1024 float    =  4096
constexpr int SM_SIDX = 70144;                 // 128 int       =   512
constexpr int SM_TOTAL = 70656;                // 69 KB -> 2 blocks/CU

__global__ __launch_bounds__(BLOCK, 2) void vq_kernel(
    const float4* __restrict__ z4g, const float4* __restrict__ cb4,
    float4* __restrict__ out4) {
  __shared__ __align__(16) char smem[SM_TOTAL];
  float4* zt4 = (float4*)(smem + SM_ZT);    // [d4][PAD]
  float4* ct4 = (float4*)(smem + SM_CT);    // [d4][PAD]
  float* scsq = (float*)(smem + SM_CSQ);    // [1024]
  int* sidx = (int*)(smem + SM_SIDX);       // [128]
  float* red_d = (float*)(smem + SM_ZT);                  // [128][17]
  int* red_k = (int*)(smem + SM_ZT + MQ * 17 * 4);        // [128][17]

  const int tid = threadIdx.x;
  const int tx = tid & 15;   // code column group
  const int ty = tid >> 4;   // query row group

  // --- Codebook norms: thread handles codes tid*4 .. tid*4+3 (cb is L2-hot).
#pragma unroll
  for (int kk = 0; kk < 4; ++kk) {
    const int k = tid * 4 + kk;
    const float4* c = cb4 + (size_t)k * D4;
    float s0 = 0.f, s1 = 0.f, s2 = 0.f, s3 = 0.f;
#pragma unroll
    for (int e = 0; e < D4; ++e) {
      const float4 v = c[e];
      s0 = fmaf(v.x, v.x, s0);
      s1 = fmaf(v.y, v.y, s1);
      s2 = fmaf(v.z, v.z, s2);
      s3 = fmaf(v.w, v.w, s3);
    }
    scsq[k] = (s0 + s1) + (s2 + s3);
  }

  // --- Stage z tile (128 queries x 64 d), transposed to [d4][q]. Coalesced:
  // consecutive lanes read consecutive float4s of global z.
  const size_t zbase = (size_t)blockIdx.x * MQ * D4;
#pragma unroll
  for (int r = 0; r < MQ * D4 / BLOCK; ++r) {
    const int f = r * BLOCK + tid;
    const int q = f >> 4, d4 = f & 15;
    zt4[d4 * PAD + q] = z4g[zbase + f];
  }

  float best[8];
  int bestk[8];
#pragma unroll
  for (int i = 0; i < 8; ++i) { best[i] = 3.402823466e38f; bestk[i] = 0; }

  for (int t = 0; t < NTILES; ++t) {
    __syncthreads();  // prior tile's ct4 reads done before overwrite
    // Stage code tile t (128 codes), transposed to [d4][c]. Coalesced.
#pragma unroll
    for (int r = 0; r < NK * D4 / BLOCK; ++r) {
      const int f = r * BLOCK + tid;
      const int c = f >> 4, d4 = f & 15;
      ct4[d4 * PAD + c] = cb4[(size_t)t * NK * D4 + f];
    }
    __syncthreads();  // staging visible (covers zt4/scsq on t==0)

    float acc[8][8];
#pragma unroll
    for (int i = 0; i < 8; ++i)
#pragma unroll
      for (int j = 0; j < 8; ++j) acc[i][j] = 0.f;

#pragma unroll 2
    for (int d4 = 0; d4 < D4; ++d4) {
      float4 zf[8], cf[8];
#pragma unroll
      for (int i = 0; i < 8; ++i) zf[i] = zt4[d4 * PAD + ty + 16 * i];
#pragma unroll
      for (int j = 0; j < 8; ++j) cf[j] = ct4[d4 * PAD + tx + 16 * j];
#pragma unroll
      for (int i = 0; i < 8; ++i)
#pragma unroll
        for (int j = 0; j < 8; ++j) {
          acc[i][j] = fmaf(zf[i].x, cf[j].x, acc[i][j]);
          acc[i][j] = fmaf(zf[i].y, cf[j].y, acc[i][j]);
          acc[i][j] = fmaf(zf[i].z, cf[j].z, acc[i][j]);
          acc[i][j] = fmaf(zf[i].w, cf[j].w, acc[i][j]);
        }
    }

    // Distance + running argmin. Within a thread k increases with (t, j),
    // strict < keeps the first (lowest-k) minimum.
#pragma unroll
    for (int j = 0; j < 8; ++j) {
      const int k = t * NK + tx + 16 * j;
      const float cs = scsq[k];
#pragma unroll
      for (int i = 0; i < 8; ++i) {
        const float dist = fmaf(-2.0f, acc[i][j], cs);
        if (dist < best[i]) { best[i] = dist; bestk[i] = k; }
      }
    }
  }

  __syncthreads();  // all zt4 reads done; safe to alias with red_*
#pragma unroll
  for (int i = 0; i < 8; ++i) {
    const int q = ty + 16 * i;
    red_d[q * 17 + tx] = best[i];
    red_k[q * 17 + tx] = bestk[i];
  }
  __syncthreads();

  // Cross-thread (tx) argmin per query; ties -> lower k (jnp.argmin order).
  if (tid < MQ) {
    float b = red_d[tid * 17];
    int bk = red_k[tid * 17];
#pragma unroll
    for (int x = 1; x < 16; ++x) {
      const float d = red_d[tid * 17 + x];
      const int kk = red_k[tid * 17 + x];
      if (d < b || (d == b && kk < bk)) { b = d; bk = kk; }
    }
    sidx[tid] = bk;
  }
  __syncthreads();

  // Gather winning codebook rows; coalesced float4 writes, cb L2-hot reads.
#pragma unroll
  for (int r = 0; r < MQ * D4 / BLOCK; ++r) {
    const int f = r * BLOCK + tid;
    const int q = f >> 4, e = f & 15;
    out4[zbase + f] = cb4[(size_t)sidx[q] * D4 + e];
  }
}

extern "C" void kernel_launch(void* const* d_in, const int* in_sizes, int n_in,
                              void* d_out, int out_size, void* d_ws, size_t ws_size,
                              hipStream_t stream) {
  const float4* z4 = (const float4*)d_in[0];
  const float4* cb4 = (const float4*)d_in[1];
  float4* out4 = (float4*)d_out;

  const int nq = in_sizes[0] / DIM;  // 65536
  vq_kernel<<<nq / MQ, BLOCK, 0, stream>>>(z4, cb4, out4);
}